// Round 6
// baseline (480.611 us; speedup 1.0000x reference)
//
#include <hip/hip_runtime.h>

#define N_NODES 100000
#define N_EDGES 50000
#define NNZ     800000
#define C       256

// coarse-bucket counting sort: bucket = contiguous key range.
#define SHC_E 8                                        // 256 edges / bucket
#define SHC_N 9                                        // 512 nodes / bucket
#define NBC_E ((N_EDGES + (1 << SHC_E) - 1) >> SHC_E)  // 196
#define NBC_N ((N_NODES + (1 << SHC_N) - 1) >> SHC_N)  // 196
#define CHUNK 4096
#define NCHUNK ((NNZ + CHUNK - 1) / CHUNK)             // 196

#define CONV_BLOCKS (N_NODES * C / 4 / 256)            // 25600
#define PREPW_BLOCKS 32

typedef short  bf16x8 __attribute__((ext_vector_type(8)));
typedef float  f32x4  __attribute__((ext_vector_type(4)));

static __device__ __forceinline__ unsigned short f2bf(float f) {
    unsigned int u = __float_as_uint(f);
    u += 0x7FFF + ((u >> 16) & 1);   // round-to-nearest-even
    return (unsigned short)(u >> 16);
}
static __device__ __forceinline__ float bf2f(unsigned short u) {
    return __uint_as_float(((unsigned int)u) << 16);
}

// ------- fused x0->bf16 conversion + per-chunk coarse histogram + prep_w -----
// Histogram blocks ONLY write their per-chunk LDS histograms to chunkhist;
// all global sums/prefixes are derived deterministically downstream (no
// global atomics anywhere in the sort path).

__global__ void convert_hist(const float* __restrict__ x0, unsigned short* __restrict__ x0b,
                             const int* __restrict__ node_idx, const int* __restrict__ edge_idx,
                             int* __restrict__ chunkhist_e, int* __restrict__ chunkhist_n,
                             const float* __restrict__ W, unsigned short* __restrict__ Wb) {
    int bid = blockIdx.x;
    if (bid < CONV_BLOCKS) {
        size_t i = (size_t)bid * 256 + threadIdx.x;   // float4 index
        float4 v = ((const float4*)x0)[i];
        ushort4 o;
        o.x = f2bf(v.x); o.y = f2bf(v.y); o.z = f2bf(v.z); o.w = f2bf(v.w);
        ((ushort4*)x0b)[i] = o;
    } else if (bid < CONV_BLOCKS + NCHUNK) {
        __shared__ int he[NBC_E], hn[NBC_N];
        const int tid = threadIdx.x;
        const int chunk = bid - CONV_BLOCKS;
        for (int i = tid; i < NBC_E; i += 256) he[i] = 0;
        for (int i = tid; i < NBC_N; i += 256) hn[i] = 0;
        __syncthreads();
        const int start = chunk * CHUNK;
        const int end = (start + CHUNK < NNZ) ? start + CHUNK : NNZ;
        for (int k = start + tid; k < end; k += 256) {
            atomicAdd(&he[edge_idx[k] >> SHC_E], 1);
            atomicAdd(&hn[node_idx[k] >> SHC_N], 1);
        }
        __syncthreads();
        for (int i = tid; i < NBC_E; i += 256) chunkhist_e[chunk * NBC_E + i] = he[i];
        for (int i = tid; i < NBC_N; i += 256) chunkhist_n[chunk * NBC_N + i] = hn[i];
    } else {
        // prep_w: W -> bf16, pre-swizzled to the GEMM's LDS layout
        int idx = (bid - CONV_BLOCKS - NCHUNK) * 256 + threadIdx.x;   // 0..8191
        int h = idx >> 12, i = idx & 4095;
        int t = i >> 9, s = (i >> 6) & 7, l = i & 63;
        int m = l & 15, q = l >> 4;
        const float* src = W + (size_t)(h * 128 + 16 * t + m) * C + 32 * s + 8 * q;
        float4 f0 = *(const float4*)(src);
        float4 f1 = *(const float4*)(src + 4);
        unsigned short* d = Wb + (size_t)idx * 8;
        d[0] = f2bf(f0.x); d[1] = f2bf(f0.y); d[2] = f2bf(f0.z); d[3] = f2bf(f0.w);
        d[4] = f2bf(f1.x); d[5] = f2bf(f1.y); d[6] = f2bf(f1.z); d[7] = f2bf(f1.w);
    }
}

// ------------- coarse exclusive scan over chunkhist column sums -> gbase -----
// block 0 = edges, block 1 = nodes. Deterministic, no atomics.

__global__ void coarse_scan(const int* __restrict__ chunkhist_e, const int* __restrict__ chunkhist_n,
                            int* __restrict__ gbase_e, int* __restrict__ gbase_n) {
    const int* ch = (blockIdx.x == 0) ? chunkhist_e : chunkhist_n;
    int* gbase = (blockIdx.x == 0) ? gbase_e : gbase_n;
    const int nb = (blockIdx.x == 0) ? NBC_E : NBC_N;   // both 196
    int tid = threadIdx.x, lane = tid & 63, wid = tid >> 6;
    int v = 0;
    if (tid < nb)
        for (int c = 0; c < NCHUNK; c++) v += ch[c * nb + tid];
    int incl = v;
#pragma unroll
    for (int s = 1; s < 64; s <<= 1) { int u = __shfl_up(incl, s, 64); if (lane >= s) incl += u; }
    __shared__ int wsum[4];
    if (lane == 63) wsum[wid] = incl;
    __syncthreads();
    int add = 0;
    for (int i = 0; i < wid; i++) add += wsum[i];
    int excl = add + incl - v;
    if (tid <= nb) gbase[tid] = excl;        // gbase[nb] = NNZ
}

// ---------------- permutation build: counting-sort partition ----------------
// Phase B (bin_coarse): per-chunk region bases computed DETERMINISTICALLY as
//   gbase[i] + prefix_{c<chunk} chunkhist[c][i] (coalesced L2 reads, 0 atomics),
//   then LDS-cursor scatter into the reserved regions.

__global__ __launch_bounds__(256) void bin_coarse(const int* __restrict__ node_idx,
                                                  const int* __restrict__ edge_idx,
                                                  const int* __restrict__ gbase_e,
                                                  const int* __restrict__ gbase_n,
                                                  const int* __restrict__ chunkhist_e,
                                                  const int* __restrict__ chunkhist_n,
                                                  unsigned int* __restrict__ tmp_e,
                                                  unsigned int* __restrict__ tmp_n) {
    __shared__ int hist_e[NBC_E], hist_n[NBC_N];
    __shared__ int base_e[NBC_E], base_n[NBC_N];
    const int tid = threadIdx.x;
    const int chunk = blockIdx.x;
    const int start = chunk * CHUNK;
    const int end = (start + CHUNK < NNZ) ? start + CHUNK : NNZ;

    for (int i = tid; i < NBC_E; i += 256) {
        int pre = gbase_e[i];
        for (int c = 0; c < chunk; c++) pre += chunkhist_e[c * NBC_E + i];
        base_e[i] = pre;
        hist_e[i] = 0;
    }
    for (int i = tid; i < NBC_N; i += 256) {
        int pre = gbase_n[i];
        for (int c = 0; c < chunk; c++) pre += chunkhist_n[c * NBC_N + i];
        base_n[i] = pre;
        hist_n[i] = 0;
    }
    __syncthreads();

    for (int k = start + tid; k < end; k += 256) {
        int ni = node_idx[k], ei = edge_idx[k];
        int be = ei >> SHC_E;
        int pe = base_e[be] + atomicAdd(&hist_e[be], 1);
        tmp_e[pe] = ((unsigned int)ni << SHC_E) | (unsigned int)(ei & ((1 << SHC_E) - 1));
        int bn = ni >> SHC_N;
        int pn = base_n[bn] + atomicAdd(&hist_n[bn], 1);
        tmp_n[pn] = ((unsigned int)ei << SHC_N) | (unsigned int)(ni & ((1 << SHC_N) - 1));
    }
}

// Phase C (scatter_fine): per coarse bucket — LDS fine histogram + scan,
// writes the off[] slice, scatters perm into the bucket's contiguous window.

template <int SHC, int NTOT>
static __device__ __forceinline__ void scatter_fine_body(const unsigned int* __restrict__ tmp,
                                                         const int* __restrict__ gbase,
                                                         int* __restrict__ off,
                                                         int* __restrict__ perm,
                                                         int b, int* hist, int* cur, int* wsum) {
    constexpr int NK = 1 << SHC;
    const int tid = threadIdx.x, lane = tid & 63, wid = tid >> 6;
    const int start = gbase[b], end = gbase[b + 1];
    for (int t = tid; t < NK; t += 256) hist[t] = 0;
    __syncthreads();
    for (int k = start + tid; k < end; k += 256)
        atomicAdd(&hist[tmp[k] & (NK - 1)], 1);
    __syncthreads();
    int v0, v1 = 0, local;
    if constexpr (NK == 512) { v0 = hist[2 * tid]; v1 = hist[2 * tid + 1]; local = v0 + v1; }
    else                     { v0 = hist[tid]; local = v0; }
    int incl = local;
#pragma unroll
    for (int s = 1; s < 64; s <<= 1) { int u = __shfl_up(incl, s, 64); if (lane >= s) incl += u; }
    if (lane == 63) wsum[wid] = incl;
    __syncthreads();
    int add = 0;
    for (int i = 0; i < wid; i++) add += wsum[i];
    int base = start + add + incl - local;   // absolute exclusive position
    const int kbase = b << SHC;
    if constexpr (NK == 512) {
        int key0 = kbase + 2 * tid;
        if (key0 < NTOT)     off[key0] = base;
        if (key0 + 1 < NTOT) off[key0 + 1] = base + v0;
        cur[2 * tid]     = base;
        cur[2 * tid + 1] = base + v0;
    } else {
        int key0 = kbase + tid;
        if (key0 < NTOT) off[key0] = base;
        cur[tid] = base;
    }
    if (b == ((NTOT - 1) >> SHC) && tid == 0) off[NTOT] = end;   // = NNZ
    __syncthreads();
    for (int k = start + tid; k < end; k += 256) {
        unsigned int u = tmp[k];
        int pos = atomicAdd(&cur[u & (NK - 1)], 1);
        perm[pos] = (int)(u >> SHC);
    }
}

__global__ __launch_bounds__(256) void scatter_fine(const unsigned int* __restrict__ tmp_e,
                                                    const unsigned int* __restrict__ tmp_n,
                                                    const int* __restrict__ gbase_e,
                                                    const int* __restrict__ gbase_n,
                                                    int* __restrict__ off_e, int* __restrict__ off_n,
                                                    int* __restrict__ perm_e, int* __restrict__ perm_n) {
    __shared__ int hist[1 << SHC_N], cur[1 << SHC_N], wsum[4];
    if (blockIdx.x < NBC_E)
        scatter_fine_body<SHC_E, N_EDGES>(tmp_e, gbase_e, off_e, perm_e, blockIdx.x, hist, cur, wsum);
    else
        scatter_fine_body<SHC_N, N_NODES>(tmp_n, gbase_n, off_n, perm_n, blockIdx.x - NBC_E, hist, cur, wsum);
}

// ---------------- segment-sum pulls: pair-gather ----------------------------
// Wave: lo half handles even rows, hi half odd rows; 16 B/lane per row.
// pull_edge (avg deg 16): 16-row main loop = 8 x 1 KB gathers in flight.

__global__ void pull_edge(const unsigned short* __restrict__ x0b,
                          const int* __restrict__ off, const int* __restrict__ perm,
                          float* __restrict__ x1, unsigned short* __restrict__ x1b) {
    int e = blockIdx.x * 4 + (threadIdx.x >> 6);
    int lane = threadIdx.x & 63;
    int half = lane >> 5;
    int cl = lane & 31;
    int s0 = off[e], s1 = off[e + 1];
    float a[8] = {0, 0, 0, 0, 0, 0, 0, 0};
    float b[8] = {0, 0, 0, 0, 0, 0, 0, 0};
    int k = s0;
    for (; k + 16 <= s1; k += 16) {
        int r0 = perm[k + half],      r1 = perm[k + 2 + half];
        int r2 = perm[k + 4 + half],  r3 = perm[k + 6 + half];
        int r4 = perm[k + 8 + half],  r5 = perm[k + 10 + half];
        int r6 = perm[k + 12 + half], r7 = perm[k + 14 + half];
        bf16x8 u0 = *(const bf16x8*)(x0b + (size_t)r0 * C + cl * 8);
        bf16x8 u1 = *(const bf16x8*)(x0b + (size_t)r1 * C + cl * 8);
        bf16x8 u2 = *(const bf16x8*)(x0b + (size_t)r2 * C + cl * 8);
        bf16x8 u3 = *(const bf16x8*)(x0b + (size_t)r3 * C + cl * 8);
        bf16x8 u4 = *(const bf16x8*)(x0b + (size_t)r4 * C + cl * 8);
        bf16x8 u5 = *(const bf16x8*)(x0b + (size_t)r5 * C + cl * 8);
        bf16x8 u6 = *(const bf16x8*)(x0b + (size_t)r6 * C + cl * 8);
        bf16x8 u7 = *(const bf16x8*)(x0b + (size_t)r7 * C + cl * 8);
#pragma unroll
        for (int j = 0; j < 8; j++) {
            a[j] += bf2f((unsigned short)u0[j]); b[j] += bf2f((unsigned short)u1[j]);
            a[j] += bf2f((unsigned short)u2[j]); b[j] += bf2f((unsigned short)u3[j]);
            a[j] += bf2f((unsigned short)u4[j]); b[j] += bf2f((unsigned short)u5[j]);
            a[j] += bf2f((unsigned short)u6[j]); b[j] += bf2f((unsigned short)u7[j]);
        }
    }
    for (; k + 8 <= s1; k += 8) {
        int r0 = perm[k + half],     r1 = perm[k + 2 + half];
        int r2 = perm[k + 4 + half], r3 = perm[k + 6 + half];
        bf16x8 u0 = *(const bf16x8*)(x0b + (size_t)r0 * C + cl * 8);
        bf16x8 u1 = *(const bf16x8*)(x0b + (size_t)r1 * C + cl * 8);
        bf16x8 u2 = *(const bf16x8*)(x0b + (size_t)r2 * C + cl * 8);
        bf16x8 u3 = *(const bf16x8*)(x0b + (size_t)r3 * C + cl * 8);
#pragma unroll
        for (int j = 0; j < 8; j++) {
            a[j] += bf2f((unsigned short)u0[j]); b[j] += bf2f((unsigned short)u1[j]);
            a[j] += bf2f((unsigned short)u2[j]); b[j] += bf2f((unsigned short)u3[j]);
        }
    }
    for (; k + 2 <= s1; k += 2) {
        int r = perm[k + half];
        bf16x8 u = *(const bf16x8*)(x0b + (size_t)r * C + cl * 8);
#pragma unroll
        for (int j = 0; j < 8; j++) a[j] += bf2f((unsigned short)u[j]);
    }
    if (k < s1 && half == 0) {   // single leftover row: lo half only
        int r = perm[k];
        bf16x8 u = *(const bf16x8*)(x0b + (size_t)r * C + cl * 8);
#pragma unroll
        for (int j = 0; j < 8; j++) a[j] += bf2f((unsigned short)u[j]);
    }
#pragma unroll
    for (int j = 0; j < 8; j++) a[j] += b[j];
#pragma unroll
    for (int j = 0; j < 8; j++) a[j] += __shfl_down(a[j], 32);
    if (half == 0) {
        f32x4 vlo = {a[0], a[1], a[2], a[3]};
        f32x4 vhi = {a[4], a[5], a[6], a[7]};
        __builtin_nontemporal_store(vlo, (f32x4*)(x1 + (size_t)e * C + cl * 8));
        __builtin_nontemporal_store(vhi, (f32x4*)(x1 + (size_t)e * C + cl * 8 + 4));
        bf16x8 o;
#pragma unroll
        for (int j = 0; j < 8; j++) o[j] = (short)f2bf(a[j]);
        *(bf16x8*)(x1b + (size_t)e * C + cl * 8) = o;
    }
}

__global__ void pull_node(const unsigned short* __restrict__ x0b,
                          const unsigned short* __restrict__ x1b,
                          const int* __restrict__ off, const int* __restrict__ perm,
                          unsigned short* __restrict__ xm) {
    int n = blockIdx.x * 4 + (threadIdx.x >> 6);
    int lane = threadIdx.x & 63;
    int half = lane >> 5;
    int cl = lane & 31;
    int s0 = off[n], s1 = off[n + 1];
    float a[8] = {0, 0, 0, 0, 0, 0, 0, 0};
    float b[8] = {0, 0, 0, 0, 0, 0, 0, 0};
    int k = s0;
    for (; k + 8 <= s1; k += 8) {
        int r0 = perm[k + half],     r1 = perm[k + 2 + half];
        int r2 = perm[k + 4 + half], r3 = perm[k + 6 + half];
        bf16x8 u0 = *(const bf16x8*)(x1b + (size_t)r0 * C + cl * 8);
        bf16x8 u1 = *(const bf16x8*)(x1b + (size_t)r1 * C + cl * 8);
        bf16x8 u2 = *(const bf16x8*)(x1b + (size_t)r2 * C + cl * 8);
        bf16x8 u3 = *(const bf16x8*)(x1b + (size_t)r3 * C + cl * 8);
#pragma unroll
        for (int j = 0; j < 8; j++) {
            a[j] += bf2f((unsigned short)u0[j]); b[j] += bf2f((unsigned short)u1[j]);
            a[j] += bf2f((unsigned short)u2[j]); b[j] += bf2f((unsigned short)u3[j]);
        }
    }
    for (; k + 2 <= s1; k += 2) {
        int r = perm[k + half];
        bf16x8 u = *(const bf16x8*)(x1b + (size_t)r * C + cl * 8);
#pragma unroll
        for (int j = 0; j < 8; j++) a[j] += bf2f((unsigned short)u[j]);
    }
    if (k < s1 && half == 0) {
        int r = perm[k];
        bf16x8 u = *(const bf16x8*)(x1b + (size_t)r * C + cl * 8);
#pragma unroll
        for (int j = 0; j < 8; j++) a[j] += bf2f((unsigned short)u[j]);
    }
#pragma unroll
    for (int j = 0; j < 8; j++) a[j] += b[j];
#pragma unroll
    for (int j = 0; j < 8; j++) a[j] += __shfl_down(a[j], 32);
    if (half == 0) {
        bf16x8 xr = *(const bf16x8*)(x0b + (size_t)n * C + cl * 8);
        bf16x8 o;
#pragma unroll
        for (int j = 0; j < 8; j++) o[j] = (short)f2bf(a[j] + bf2f((unsigned short)xr[j]));
        *(bf16x8*)(xm + (size_t)n * C + cl * 8) = o;
    }
}

// ------ MFMA GEMM: one block per 128-row tile, BOTH col halves --------------
// W-halves staged sequentially into the same 64 KB LDS buffer; A-frags loaded
// once (xm read 51 MB instead of 102). 2 blocks/CU by LDS.

__global__ __launch_bounds__(512) void mfma_gemm3(const unsigned short* __restrict__ xm,
                                                  const unsigned short* __restrict__ Wb,
                                                  const float* __restrict__ bias,
                                                  float* __restrict__ out) {
    __shared__ unsigned short Bs[4096 * 8];   // 64 KB
    const int rt = blockIdx.x;
    const int tid = threadIdx.x;
    const int w = tid >> 6, lane = tid & 63;
    const int m = lane & 15, q = lane >> 4;
    const int row = rt * 128 + w * 16 + m;
    const int arow = row < N_NODES ? row : N_NODES - 1;   // clamp tail (stores guarded)

    bf16x8 a[8];
    const unsigned short* ap = xm + (size_t)arow * C + q * 8;
#pragma unroll
    for (int s = 0; s < 8; s++) a[s] = *(const bf16x8*)(ap + 32 * s);

    const int r0 = rt * 128 + w * 16 + q * 4;

    for (int h = 0; h < 2; h++) {
        __syncthreads();   // h=0: before first use; h=1: all Bs reads of h=0 done
        const unsigned short* wsrc = Wb + (size_t)h * (4096 * 8);
#pragma unroll
        for (int it = 0; it < 8; it++) {
            int i = it * 512 + tid;
            *(bf16x8*)(Bs + (size_t)i * 8) = *(const bf16x8*)(wsrc + (size_t)i * 8);
        }
        __syncthreads();

        f32x4 acc[8];
#pragma unroll
        for (int t = 0; t < 8; t++) acc[t] = (f32x4){0.f, 0.f, 0.f, 0.f};
#pragma unroll
        for (int s = 0; s < 8; s++) {
#pragma unroll
            for (int t = 0; t < 8; t++) {
                bf16x8 b = *(const bf16x8*)(Bs + ((t * 8 + s) * 64 + lane) * 8);
                acc[t] = __builtin_amdgcn_mfma_f32_16x16x32_bf16(a[s], b, acc[t], 0, 0, 0);
            }
        }

        const int colbase = h * 128;
#pragma unroll
        for (int t = 0; t < 8; t++) {
            float bv = bias[colbase + t * 16 + m];
#pragma unroll
            for (int r = 0; r < 4; r++) {
                int rr = r0 + r;
                if (rr < N_NODES)
                    __builtin_nontemporal_store(acc[t][r] + bv,
                                                out + (size_t)rr * C + colbase + t * 16 + m);
            }
        }
    }
}

// ---------------- fallback (round-1 path, used only if ws too small) --------

__global__ void init_kernel(const float* __restrict__ x0, float* __restrict__ out) {
    long long i = (long long)blockIdx.x * blockDim.x + threadIdx.x;
    const long long n_node4 = (long long)N_NODES * C / 4;
    const long long n_tot4  = (long long)(N_NODES + N_EDGES) * C / 4;
    float4* o4 = (float4*)out;
    if (i < n_node4)      o4[i] = ((const float4*)x0)[i];
    else if (i < n_tot4)  o4[i] = make_float4(0.f, 0.f, 0.f, 0.f);
}

__global__ void scatter_add_kernel(const float* __restrict__ src,
                                   const int* __restrict__ src_idx,
                                   const int* __restrict__ dst_idx,
                                   float* __restrict__ dst) {
    int j    = blockIdx.x * (blockDim.x >> 6) + (threadIdx.x >> 6);
    int lane = threadIdx.x & 63;
    if (j >= NNZ) return;
    int s = src_idx[j];
    int d = dst_idx[j];
    const float4 v = *(const float4*)(src + (long long)s * C + lane * 4);
    float* dp = dst + (long long)d * C + lane * 4;
    atomicAdd(dp + 0, v.x); atomicAdd(dp + 1, v.y);
    atomicAdd(dp + 2, v.z); atomicAdd(dp + 3, v.w);
}

__global__ void gin_gemm_kernel(const float* __restrict__ W,
                                const float* __restrict__ b,
                                float* __restrict__ out) {
    int n = blockIdx.x;
    int t = threadIdx.x;
    __shared__ float xs[C];
    float* row = out + (long long)n * C;
    xs[t] = row[t];
    __syncthreads();
    float acc = b[t];
    const float* wrow = W + t * C;
#pragma unroll 8
    for (int k = 0; k < C; k += 4) {
        float4 xv = *(const float4*)(xs + k);
        float4 wv = *(const float4*)(wrow + k);
        acc = fmaf(xv.x, wv.x, acc); acc = fmaf(xv.y, wv.y, acc);
        acc = fmaf(xv.z, wv.z, acc); acc = fmaf(xv.w, wv.w, acc);
    }
    row[t] = acc;
}

// ---------------------------------------------------------------------------

extern "C" void kernel_launch(void* const* d_in, const int* in_sizes, int n_in,
                              void* d_out, int out_size, void* d_ws, size_t ws_size,
                              hipStream_t stream) {
    const float* x0       = (const float*)d_in[0];
    const int*   node_idx = (const int*)d_in[1];
    const int*   edge_idx = (const int*)d_in[2];
    const float* W        = (const float*)d_in[3];
    const float* b        = (const float*)d_in[4];
    float* out = (float*)d_out;
    float* x1  = out + (size_t)N_NODES * C;   // output 1

    char* p = (char*)d_ws;
    size_t used = 0;
    auto alloc = [&](size_t bytes) {
        char* r = p + used;
        used += (bytes + 255) & ~(size_t)255;
        return r;
    };
    int* off_e   = (int*)alloc((N_EDGES + 1) * 4);
    int* off_n   = (int*)alloc((N_NODES + 1) * 4);
    int* gbase_e = (int*)alloc((NBC_E + 1) * 4);
    int* gbase_n = (int*)alloc((NBC_N + 1) * 4);
    int* chunkhist_e = (int*)alloc((size_t)NCHUNK * NBC_E * 4);
    int* chunkhist_n = (int*)alloc((size_t)NCHUNK * NBC_N * 4);
    int* perm_e  = (int*)alloc((size_t)NNZ * 4);
    int* perm_n  = (int*)alloc((size_t)NNZ * 4);
    unsigned short* Wb  = (unsigned short*)alloc((size_t)2 * 4096 * 8 * 2);
    unsigned short* x0b = (unsigned short*)alloc((size_t)N_NODES * C * 2);
    unsigned short* x1b = (unsigned short*)alloc((size_t)N_EDGES * C * 2);
    unsigned short* xm  = (unsigned short*)alloc((size_t)N_NODES * C * 2);

    if (ws_size < used) {
        long long tot4 = (long long)(N_NODES + N_EDGES) * C / 4;
        init_kernel<<<(int)((tot4 + 255) / 256), 256, 0, stream>>>(x0, out);
        int grid = NNZ / 4;
        scatter_add_kernel<<<grid, 256, 0, stream>>>(x0, node_idx, edge_idx, x1);
        scatter_add_kernel<<<grid, 256, 0, stream>>>(x1, edge_idx, node_idx, out);
        gin_gemm_kernel<<<N_NODES, 256, 0, stream>>>(W, b, out);
        return;
    }

    // fused x0->bf16 conversion + per-chunk coarse histogram + prep_w
    convert_hist<<<CONV_BLOCKS + NCHUNK + PREPW_BLOCKS, 256, 0, stream>>>(
        x0, x0b, node_idx, edge_idx, chunkhist_e, chunkhist_n, W, Wb);

    // coarse exclusive scan (column sums of chunkhist) -> bucket region bases
    coarse_scan<<<2, 256, 0, stream>>>(chunkhist_e, chunkhist_n, gbase_e, gbase_n);

    // permutation build: deterministic counting-sort partition (0 global atomics).
    // tmp arrays alias x1b/xm: both are dead until pull_edge/pull_node, which
    // run strictly after scatter_fine consumed tmp (same stream).
    unsigned int* tmp_e = (unsigned int*)x1b;
    unsigned int* tmp_n = (unsigned int*)xm;
    bin_coarse<<<NCHUNK, 256, 0, stream>>>(node_idx, edge_idx, gbase_e, gbase_n,
                                           chunkhist_e, chunkhist_n, tmp_e, tmp_n);
    // scatter_fine also builds off[] (per-bucket LDS histogram + scan)
    scatter_fine<<<NBC_E + NBC_N, 256, 0, stream>>>(tmp_e, tmp_n, gbase_e, gbase_n,
                                                    off_e, off_n, perm_e, perm_n);

    // pulls (pair-gather; edge kernel 8 gathers deep)
    pull_edge<<<N_EDGES / 4, 256, 0, stream>>>(x0b, off_e, perm_e, x1, x1b);
    pull_node<<<N_NODES / 4, 256, 0, stream>>>(x0b, x1b, off_n, perm_n, xm);

    // GEMM: out0 = xm @ W^T + b (one block per row tile, both col halves)
    const int row_tiles = (N_NODES + 127) / 128;   // 782
    mfma_gemm3<<<row_tiles, 512, 0, stream>>>(xm, Wb, b, out);
}

// Round 7
// 429.718 us; speedup vs baseline: 1.1184x; 1.1184x over previous
//
#include <hip/hip_runtime.h>

#define N_NODES 100000
#define N_EDGES 50000
#define NNZ     800000
#define C       256

// coarse-bucket counting sort: bucket = contiguous key range.
#define SHC_E 8                                        // 256 edges / bucket
#define SHC_N 9                                        // 512 nodes / bucket
#define NBC_E ((N_EDGES + (1 << SHC_E) - 1) >> SHC_E)  // 196
#define NBC_N ((N_NODES + (1 << SHC_N) - 1) >> SHC_N)  // 196
#define CHUNK 4096
#define NCHUNK ((NNZ + CHUNK - 1) / CHUNK)             // 196

#define CONV_BLOCKS (N_NODES * C / 4 / 256)            // 25600
#define PREPW_BLOCKS 32

typedef short  bf16x8 __attribute__((ext_vector_type(8)));
typedef float  f32x4  __attribute__((ext_vector_type(4)));

static __device__ __forceinline__ unsigned short f2bf(float f) {
    unsigned int u = __float_as_uint(f);
    u += 0x7FFF + ((u >> 16) & 1);   // round-to-nearest-even
    return (unsigned short)(u >> 16);
}
static __device__ __forceinline__ float bf2f(unsigned short u) {
    return __uint_as_float(((unsigned int)u) << 16);
}

// ------- fused x0->bf16 conversion + per-chunk coarse histogram + prep_w -----

__global__ void convert_hist(const float* __restrict__ x0, unsigned short* __restrict__ x0b,
                             const int* __restrict__ node_idx, const int* __restrict__ edge_idx,
                             int* __restrict__ chunkhist_e, int* __restrict__ chunkhist_n,
                             const float* __restrict__ W, unsigned short* __restrict__ Wb) {
    int bid = blockIdx.x;
    if (bid < CONV_BLOCKS) {
        size_t i = (size_t)bid * 256 + threadIdx.x;   // float4 index
        float4 v = ((const float4*)x0)[i];
        ushort4 o;
        o.x = f2bf(v.x); o.y = f2bf(v.y); o.z = f2bf(v.z); o.w = f2bf(v.w);
        ((ushort4*)x0b)[i] = o;
    } else if (bid < CONV_BLOCKS + NCHUNK) {
        __shared__ int he[NBC_E], hn[NBC_N];
        const int tid = threadIdx.x;
        const int chunk = bid - CONV_BLOCKS;
        for (int i = tid; i < NBC_E; i += 256) he[i] = 0;
        for (int i = tid; i < NBC_N; i += 256) hn[i] = 0;
        __syncthreads();
        const int start = chunk * CHUNK;
        const int end = (start + CHUNK < NNZ) ? start + CHUNK : NNZ;
        for (int k = start + tid; k < end; k += 256) {
            atomicAdd(&he[edge_idx[k] >> SHC_E], 1);
            atomicAdd(&hn[node_idx[k] >> SHC_N], 1);
        }
        __syncthreads();
        for (int i = tid; i < NBC_E; i += 256) chunkhist_e[chunk * NBC_E + i] = he[i];
        for (int i = tid; i < NBC_N; i += 256) chunkhist_n[chunk * NBC_N + i] = hn[i];
    } else {
        // prep_w: W -> bf16, pre-swizzled to the GEMM's LDS layout
        int idx = (bid - CONV_BLOCKS - NCHUNK) * 256 + threadIdx.x;   // 0..8191
        int h = idx >> 12, i = idx & 4095;
        int t = i >> 9, s = (i >> 6) & 7, l = i & 63;
        int m = l & 15, q = l >> 4;
        const float* src = W + (size_t)(h * 128 + 16 * t + m) * C + 32 * s + 8 * q;
        float4 f0 = *(const float4*)(src);
        float4 f1 = *(const float4*)(src + 4);
        unsigned short* d = Wb + (size_t)idx * 8;
        d[0] = f2bf(f0.x); d[1] = f2bf(f0.y); d[2] = f2bf(f0.z); d[3] = f2bf(f0.w);
        d[4] = f2bf(f1.x); d[5] = f2bf(f1.y); d[6] = f2bf(f1.z); d[7] = f2bf(f1.w);
    }
}

// ------------- per-bin scan over chunks (in place) ---------------------------
// One block per bin (NBC_E + NBC_N blocks). Replaces chunkhist[c][bin] with
// the exclusive prefix over chunks; writes the bin total to binsum.
// Parallel (196-wide block scan) -- no serial per-chunk loops anywhere.

__global__ void scan_chunks(int* __restrict__ chunkhist_e, int* __restrict__ chunkhist_n,
                            int* __restrict__ binsum_e, int* __restrict__ binsum_n) {
    bool isE = blockIdx.x < NBC_E;
    int* ch = isE ? chunkhist_e : chunkhist_n;
    int* binsum = isE ? binsum_e : binsum_n;
    const int nb = isE ? NBC_E : NBC_N;
    const int bin = isE ? blockIdx.x : blockIdx.x - NBC_E;
    int tid = threadIdx.x, lane = tid & 63, wid = tid >> 6;
    int v = (tid < NCHUNK) ? ch[tid * nb + bin] : 0;
    int incl = v;
#pragma unroll
    for (int s = 1; s < 64; s <<= 1) { int u = __shfl_up(incl, s, 64); if (lane >= s) incl += u; }
    __shared__ int wsum[4];
    if (lane == 63) wsum[wid] = incl;
    __syncthreads();
    int add = 0;
    for (int i = 0; i < wid; i++) add += wsum[i];
    int excl = add + incl - v;
    if (tid < NCHUNK) ch[tid * nb + bin] = excl;
    if (tid == NCHUNK - 1) binsum[bin] = excl + v;
}

// ------------- coarse exclusive scan of bin totals -> gbase ------------------

__global__ void coarse_scan(const int* __restrict__ binsum_e, const int* __restrict__ binsum_n,
                            int* __restrict__ gbase_e, int* __restrict__ gbase_n) {
    const int* binsum = (blockIdx.x == 0) ? binsum_e : binsum_n;
    int* gbase = (blockIdx.x == 0) ? gbase_e : gbase_n;
    const int nb = (blockIdx.x == 0) ? NBC_E : NBC_N;
    int tid = threadIdx.x, lane = tid & 63, wid = tid >> 6;
    int v = (tid < nb) ? binsum[tid] : 0;
    int incl = v;
#pragma unroll
    for (int s = 1; s < 64; s <<= 1) { int u = __shfl_up(incl, s, 64); if (lane >= s) incl += u; }
    __shared__ int wsum[4];
    if (lane == 63) wsum[wid] = incl;
    __syncthreads();
    int add = 0;
    for (int i = 0; i < wid; i++) add += wsum[i];
    int excl = add + incl - v;
    if (tid <= nb) gbase[tid] = excl;        // gbase[nb] = NNZ
}

// ---------------- permutation build: counting-sort partition ----------------
// Phase B (bin_coarse): region base = gbase[i] + chunkhist[chunk][i] (the
//   pre-computed exclusive prefix) -- one coalesced read, zero atomics.

__global__ __launch_bounds__(256) void bin_coarse(const int* __restrict__ node_idx,
                                                  const int* __restrict__ edge_idx,
                                                  const int* __restrict__ gbase_e,
                                                  const int* __restrict__ gbase_n,
                                                  const int* __restrict__ chunkhist_e,
                                                  const int* __restrict__ chunkhist_n,
                                                  unsigned int* __restrict__ tmp_e,
                                                  unsigned int* __restrict__ tmp_n) {
    __shared__ int hist_e[NBC_E], hist_n[NBC_N];
    __shared__ int base_e[NBC_E], base_n[NBC_N];
    const int tid = threadIdx.x;
    const int chunk = blockIdx.x;
    const int start = chunk * CHUNK;
    const int end = (start + CHUNK < NNZ) ? start + CHUNK : NNZ;

    for (int i = tid; i < NBC_E; i += 256) {
        base_e[i] = gbase_e[i] + chunkhist_e[chunk * NBC_E + i];
        hist_e[i] = 0;
    }
    for (int i = tid; i < NBC_N; i += 256) {
        base_n[i] = gbase_n[i] + chunkhist_n[chunk * NBC_N + i];
        hist_n[i] = 0;
    }
    __syncthreads();

    for (int k = start + tid; k < end; k += 256) {
        int ni = node_idx[k], ei = edge_idx[k];
        int be = ei >> SHC_E;
        int pe = base_e[be] + atomicAdd(&hist_e[be], 1);
        tmp_e[pe] = ((unsigned int)ni << SHC_E) | (unsigned int)(ei & ((1 << SHC_E) - 1));
        int bn = ni >> SHC_N;
        int pn = base_n[bn] + atomicAdd(&hist_n[bn], 1);
        tmp_n[pn] = ((unsigned int)ei << SHC_N) | (unsigned int)(ni & ((1 << SHC_N) - 1));
    }
}

// Phase C (scatter_fine): per coarse bucket — LDS fine histogram + scan,
// writes the off[] slice, scatters perm into the bucket's contiguous window.

template <int SHC, int NTOT>
static __device__ __forceinline__ void scatter_fine_body(const unsigned int* __restrict__ tmp,
                                                         const int* __restrict__ gbase,
                                                         int* __restrict__ off,
                                                         int* __restrict__ perm,
                                                         int b, int* hist, int* cur, int* wsum) {
    constexpr int NK = 1 << SHC;
    const int tid = threadIdx.x, lane = tid & 63, wid = tid >> 6;
    const int start = gbase[b], end = gbase[b + 1];
    for (int t = tid; t < NK; t += 256) hist[t] = 0;
    __syncthreads();
    for (int k = start + tid; k < end; k += 256)
        atomicAdd(&hist[tmp[k] & (NK - 1)], 1);
    __syncthreads();
    int v0, v1 = 0, local;
    if constexpr (NK == 512) { v0 = hist[2 * tid]; v1 = hist[2 * tid + 1]; local = v0 + v1; }
    else                     { v0 = hist[tid]; local = v0; }
    int incl = local;
#pragma unroll
    for (int s = 1; s < 64; s <<= 1) { int u = __shfl_up(incl, s, 64); if (lane >= s) incl += u; }
    if (lane == 63) wsum[wid] = incl;
    __syncthreads();
    int add = 0;
    for (int i = 0; i < wid; i++) add += wsum[i];
    int base = start + add + incl - local;   // absolute exclusive position
    const int kbase = b << SHC;
    if constexpr (NK == 512) {
        int key0 = kbase + 2 * tid;
        if (key0 < NTOT)     off[key0] = base;
        if (key0 + 1 < NTOT) off[key0 + 1] = base + v0;
        cur[2 * tid]     = base;
        cur[2 * tid + 1] = base + v0;
    } else {
        int key0 = kbase + tid;
        if (key0 < NTOT) off[key0] = base;
        cur[tid] = base;
    }
    if (b == ((NTOT - 1) >> SHC) && tid == 0) off[NTOT] = end;   // = NNZ
    __syncthreads();
    for (int k = start + tid; k < end; k += 256) {
        unsigned int u = tmp[k];
        int pos = atomicAdd(&cur[u & (NK - 1)], 1);
        perm[pos] = (int)(u >> SHC);
    }
}

__global__ __launch_bounds__(256) void scatter_fine(const unsigned int* __restrict__ tmp_e,
                                                    const unsigned int* __restrict__ tmp_n,
                                                    const int* __restrict__ gbase_e,
                                                    const int* __restrict__ gbase_n,
                                                    int* __restrict__ off_e, int* __restrict__ off_n,
                                                    int* __restrict__ perm_e, int* __restrict__ perm_n) {
    __shared__ int hist[1 << SHC_N], cur[1 << SHC_N], wsum[4];
    if (blockIdx.x < NBC_E)
        scatter_fine_body<SHC_E, N_EDGES>(tmp_e, gbase_e, off_e, perm_e, blockIdx.x, hist, cur, wsum);
    else
        scatter_fine_body<SHC_N, N_NODES>(tmp_n, gbase_n, off_n, perm_n, blockIdx.x - NBC_E, hist, cur, wsum);
}

// ---------------- segment-sum pulls: pair-gather ----------------------------

__global__ void pull_edge(const unsigned short* __restrict__ x0b,
                          const int* __restrict__ off, const int* __restrict__ perm,
                          float* __restrict__ x1, unsigned short* __restrict__ x1b) {
    int e = blockIdx.x * 4 + (threadIdx.x >> 6);
    int lane = threadIdx.x & 63;
    int half = lane >> 5;
    int cl = lane & 31;
    int s0 = off[e], s1 = off[e + 1];
    float a[8] = {0, 0, 0, 0, 0, 0, 0, 0};
    float b[8] = {0, 0, 0, 0, 0, 0, 0, 0};
    int k = s0;
    for (; k + 16 <= s1; k += 16) {
        int r0 = perm[k + half],      r1 = perm[k + 2 + half];
        int r2 = perm[k + 4 + half],  r3 = perm[k + 6 + half];
        int r4 = perm[k + 8 + half],  r5 = perm[k + 10 + half];
        int r6 = perm[k + 12 + half], r7 = perm[k + 14 + half];
        bf16x8 u0 = *(const bf16x8*)(x0b + (size_t)r0 * C + cl * 8);
        bf16x8 u1 = *(const bf16x8*)(x0b + (size_t)r1 * C + cl * 8);
        bf16x8 u2 = *(const bf16x8*)(x0b + (size_t)r2 * C + cl * 8);
        bf16x8 u3 = *(const bf16x8*)(x0b + (size_t)r3 * C + cl * 8);
        bf16x8 u4 = *(const bf16x8*)(x0b + (size_t)r4 * C + cl * 8);
        bf16x8 u5 = *(const bf16x8*)(x0b + (size_t)r5 * C + cl * 8);
        bf16x8 u6 = *(const bf16x8*)(x0b + (size_t)r6 * C + cl * 8);
        bf16x8 u7 = *(const bf16x8*)(x0b + (size_t)r7 * C + cl * 8);
#pragma unroll
        for (int j = 0; j < 8; j++) {
            a[j] += bf2f((unsigned short)u0[j]); b[j] += bf2f((unsigned short)u1[j]);
            a[j] += bf2f((unsigned short)u2[j]); b[j] += bf2f((unsigned short)u3[j]);
            a[j] += bf2f((unsigned short)u4[j]); b[j] += bf2f((unsigned short)u5[j]);
            a[j] += bf2f((unsigned short)u6[j]); b[j] += bf2f((unsigned short)u7[j]);
        }
    }
    for (; k + 8 <= s1; k += 8) {
        int r0 = perm[k + half],     r1 = perm[k + 2 + half];
        int r2 = perm[k + 4 + half], r3 = perm[k + 6 + half];
        bf16x8 u0 = *(const bf16x8*)(x0b + (size_t)r0 * C + cl * 8);
        bf16x8 u1 = *(const bf16x8*)(x0b + (size_t)r1 * C + cl * 8);
        bf16x8 u2 = *(const bf16x8*)(x0b + (size_t)r2 * C + cl * 8);
        bf16x8 u3 = *(const bf16x8*)(x0b + (size_t)r3 * C + cl * 8);
#pragma unroll
        for (int j = 0; j < 8; j++) {
            a[j] += bf2f((unsigned short)u0[j]); b[j] += bf2f((unsigned short)u1[j]);
            a[j] += bf2f((unsigned short)u2[j]); b[j] += bf2f((unsigned short)u3[j]);
        }
    }
    for (; k + 2 <= s1; k += 2) {
        int r = perm[k + half];
        bf16x8 u = *(const bf16x8*)(x0b + (size_t)r * C + cl * 8);
#pragma unroll
        for (int j = 0; j < 8; j++) a[j] += bf2f((unsigned short)u[j]);
    }
    if (k < s1 && half == 0) {   // single leftover row: lo half only
        int r = perm[k];
        bf16x8 u = *(const bf16x8*)(x0b + (size_t)r * C + cl * 8);
#pragma unroll
        for (int j = 0; j < 8; j++) a[j] += bf2f((unsigned short)u[j]);
    }
#pragma unroll
    for (int j = 0; j < 8; j++) a[j] += b[j];
#pragma unroll
    for (int j = 0; j < 8; j++) a[j] += __shfl_down(a[j], 32);
    if (half == 0) {
        f32x4 vlo = {a[0], a[1], a[2], a[3]};
        f32x4 vhi = {a[4], a[5], a[6], a[7]};
        __builtin_nontemporal_store(vlo, (f32x4*)(x1 + (size_t)e * C + cl * 8));
        __builtin_nontemporal_store(vhi, (f32x4*)(x1 + (size_t)e * C + cl * 8 + 4));
        bf16x8 o;
#pragma unroll
        for (int j = 0; j < 8; j++) o[j] = (short)f2bf(a[j]);
        *(bf16x8*)(x1b + (size_t)e * C + cl * 8) = o;
    }
}

__global__ void pull_node(const unsigned short* __restrict__ x0b,
                          const unsigned short* __restrict__ x1b,
                          const int* __restrict__ off, const int* __restrict__ perm,
                          unsigned short* __restrict__ xm) {
    int n = blockIdx.x * 4 + (threadIdx.x >> 6);
    int lane = threadIdx.x & 63;
    int half = lane >> 5;
    int cl = lane & 31;
    int s0 = off[n], s1 = off[n + 1];
    float a[8] = {0, 0, 0, 0, 0, 0, 0, 0};
    float b[8] = {0, 0, 0, 0, 0, 0, 0, 0};
    int k = s0;
    for (; k + 8 <= s1; k += 8) {
        int r0 = perm[k + half],     r1 = perm[k + 2 + half];
        int r2 = perm[k + 4 + half], r3 = perm[k + 6 + half];
        bf16x8 u0 = *(const bf16x8*)(x1b + (size_t)r0 * C + cl * 8);
        bf16x8 u1 = *(const bf16x8*)(x1b + (size_t)r1 * C + cl * 8);
        bf16x8 u2 = *(const bf16x8*)(x1b + (size_t)r2 * C + cl * 8);
        bf16x8 u3 = *(const bf16x8*)(x1b + (size_t)r3 * C + cl * 8);
#pragma unroll
        for (int j = 0; j < 8; j++) {
            a[j] += bf2f((unsigned short)u0[j]); b[j] += bf2f((unsigned short)u1[j]);
            a[j] += bf2f((unsigned short)u2[j]); b[j] += bf2f((unsigned short)u3[j]);
        }
    }
    for (; k + 2 <= s1; k += 2) {
        int r = perm[k + half];
        bf16x8 u = *(const bf16x8*)(x1b + (size_t)r * C + cl * 8);
#pragma unroll
        for (int j = 0; j < 8; j++) a[j] += bf2f((unsigned short)u[j]);
    }
    if (k < s1 && half == 0) {
        int r = perm[k];
        bf16x8 u = *(const bf16x8*)(x1b + (size_t)r * C + cl * 8);
#pragma unroll
        for (int j = 0; j < 8; j++) a[j] += bf2f((unsigned short)u[j]);
    }
#pragma unroll
    for (int j = 0; j < 8; j++) a[j] += b[j];
#pragma unroll
    for (int j = 0; j < 8; j++) a[j] += __shfl_down(a[j], 32);
    if (half == 0) {
        bf16x8 xr = *(const bf16x8*)(x0b + (size_t)n * C + cl * 8);
        bf16x8 o;
#pragma unroll
        for (int j = 0; j < 8; j++) o[j] = (short)f2bf(a[j] + bf2f((unsigned short)xr[j]));
        *(bf16x8*)(xm + (size_t)n * C + cl * 8) = o;
    }
}

// ---------------- MFMA GEMM: pre-swizzled bf16 W-half staged in 64 KB LDS ----
// Two blocks per 128-row tile (one per col half) -- 1564 blocks, best tail
// quantization (round-6 lesson: one-block-both-halves loses to tail effects).

__global__ __launch_bounds__(512) void mfma_gemm2(const unsigned short* __restrict__ xm,
                                                  const unsigned short* __restrict__ Wb,
                                                  const float* __restrict__ bias,
                                                  float* __restrict__ out) {
    __shared__ unsigned short Bs[8 * 8 * 64 * 8];   // 65536 B
    const int rt = blockIdx.x >> 1;
    const int colbase = (blockIdx.x & 1) * 128;
    const int tid = threadIdx.x;

    const unsigned short* wsrc = Wb + (size_t)(blockIdx.x & 1) * (4096 * 8);
#pragma unroll
    for (int it = 0; it < 8; it++) {
        int i = it * 512 + tid;
        *(bf16x8*)(Bs + (size_t)i * 8) = *(const bf16x8*)(wsrc + (size_t)i * 8);
    }

    const int w = tid >> 6, lane = tid & 63;
    const int m = lane & 15, q = lane >> 4;
    const int row = rt * 128 + w * 16 + m;
    const int arow = row < N_NODES ? row : N_NODES - 1;   // clamp tail (stores guarded)

    bf16x8 a[8];
    const unsigned short* ap = xm + (size_t)arow * C + q * 8;
#pragma unroll
    for (int s = 0; s < 8; s++) a[s] = *(const bf16x8*)(ap + 32 * s);

    __syncthreads();

    f32x4 acc[8];
#pragma unroll
    for (int t = 0; t < 8; t++) acc[t] = (f32x4){0.f, 0.f, 0.f, 0.f};

#pragma unroll
    for (int s = 0; s < 8; s++) {
#pragma unroll
        for (int t = 0; t < 8; t++) {
            bf16x8 b = *(const bf16x8*)(Bs + ((t * 8 + s) * 64 + lane) * 8);
            acc[t] = __builtin_amdgcn_mfma_f32_16x16x32_bf16(a[s], b, acc[t], 0, 0, 0);
        }
    }

    const int r0 = rt * 128 + w * 16 + q * 4;
#pragma unroll
    for (int t = 0; t < 8; t++) {
        float bv = bias[colbase + t * 16 + m];
#pragma unroll
        for (int r = 0; r < 4; r++) {
            int rr = r0 + r;
            if (rr < N_NODES)
                __builtin_nontemporal_store(acc[t][r] + bv,
                                            out + (size_t)rr * C + colbase + t * 16 + m);
        }
    }
}

// ---------------- fallback (round-1 path, used only if ws too small) --------

__global__ void init_kernel(const float* __restrict__ x0, float* __restrict__ out) {
    long long i = (long long)blockIdx.x * blockDim.x + threadIdx.x;
    const long long n_node4 = (long long)N_NODES * C / 4;
    const long long n_tot4  = (long long)(N_NODES + N_EDGES) * C / 4;
    float4* o4 = (float4*)out;
    if (i < n_node4)      o4[i] = ((const float4*)x0)[i];
    else if (i < n_tot4)  o4[i] = make_float4(0.f, 0.f, 0.f, 0.f);
}

__global__ void scatter_add_kernel(const float* __restrict__ src,
                                   const int* __restrict__ src_idx,
                                   const int* __restrict__ dst_idx,
                                   float* __restrict__ dst) {
    int j    = blockIdx.x * (blockDim.x >> 6) + (threadIdx.x >> 6);
    int lane = threadIdx.x & 63;
    if (j >= NNZ) return;
    int s = src_idx[j];
    int d = dst_idx[j];
    const float4 v = *(const float4*)(src + (long long)s * C + lane * 4);
    float* dp = dst + (long long)d * C + lane * 4;
    atomicAdd(dp + 0, v.x); atomicAdd(dp + 1, v.y);
    atomicAdd(dp + 2, v.z); atomicAdd(dp + 3, v.w);
}

__global__ void gin_gemm_kernel(const float* __restrict__ W,
                                const float* __restrict__ b,
                                float* __restrict__ out) {
    int n = blockIdx.x;
    int t = threadIdx.x;
    __shared__ float xs[C];
    float* row = out + (long long)n * C;
    xs[t] = row[t];
    __syncthreads();
    float acc = b[t];
    const float* wrow = W + t * C;
#pragma unroll 8
    for (int k = 0; k < C; k += 4) {
        float4 xv = *(const float4*)(xs + k);
        float4 wv = *(const float4*)(wrow + k);
        acc = fmaf(xv.x, wv.x, acc); acc = fmaf(xv.y, wv.y, acc);
        acc = fmaf(xv.z, wv.z, acc); acc = fmaf(xv.w, wv.w, acc);
    }
    row[t] = acc;
}

// ---------------------------------------------------------------------------

extern "C" void kernel_launch(void* const* d_in, const int* in_sizes, int n_in,
                              void* d_out, int out_size, void* d_ws, size_t ws_size,
                              hipStream_t stream) {
    const float* x0       = (const float*)d_in[0];
    const int*   node_idx = (const int*)d_in[1];
    const int*   edge_idx = (const int*)d_in[2];
    const float* W        = (const float*)d_in[3];
    const float* b        = (const float*)d_in[4];
    float* out = (float*)d_out;
    float* x1  = out + (size_t)N_NODES * C;   // output 1

    char* p = (char*)d_ws;
    size_t used = 0;
    auto alloc = [&](size_t bytes) {
        char* r = p + used;
        used += (bytes + 255) & ~(size_t)255;
        return r;
    };
    int* off_e   = (int*)alloc((N_EDGES + 1) * 4);
    int* off_n   = (int*)alloc((N_NODES + 1) * 4);
    int* gbase_e = (int*)alloc((NBC_E + 1) * 4);
    int* gbase_n = (int*)alloc((NBC_N + 1) * 4);
    int* binsum_e = (int*)alloc(NBC_E * 4);
    int* binsum_n = (int*)alloc(NBC_N * 4);
    int* chunkhist_e = (int*)alloc((size_t)NCHUNK * NBC_E * 4);
    int* chunkhist_n = (int*)alloc((size_t)NCHUNK * NBC_N * 4);
    int* perm_e  = (int*)alloc((size_t)NNZ * 4);
    int* perm_n  = (int*)alloc((size_t)NNZ * 4);
    unsigned short* Wb  = (unsigned short*)alloc((size_t)2 * 4096 * 8 * 2);
    unsigned short* x0b = (unsigned short*)alloc((size_t)N_NODES * C * 2);
    unsigned short* x1b = (unsigned short*)alloc((size_t)N_EDGES * C * 2);
    unsigned short* xm  = (unsigned short*)alloc((size_t)N_NODES * C * 2);

    if (ws_size < used) {
        long long tot4 = (long long)(N_NODES + N_EDGES) * C / 4;
        init_kernel<<<(int)((tot4 + 255) / 256), 256, 0, stream>>>(x0, out);
        int grid = NNZ / 4;
        scatter_add_kernel<<<grid, 256, 0, stream>>>(x0, node_idx, edge_idx, x1);
        scatter_add_kernel<<<grid, 256, 0, stream>>>(x1, edge_idx, node_idx, out);
        gin_gemm_kernel<<<N_NODES, 256, 0, stream>>>(W, b, out);
        return;
    }

    // fused x0->bf16 conversion + per-chunk coarse histogram + prep_w
    convert_hist<<<CONV_BLOCKS + NCHUNK + PREPW_BLOCKS, 256, 0, stream>>>(
        x0, x0b, node_idx, edge_idx, chunkhist_e, chunkhist_n, W, Wb);

    // per-bin parallel scan over chunks (in place) + bin totals
    scan_chunks<<<NBC_E + NBC_N, 256, 0, stream>>>(chunkhist_e, chunkhist_n, binsum_e, binsum_n);

    // coarse exclusive scan of bin totals -> bucket region bases
    coarse_scan<<<2, 256, 0, stream>>>(binsum_e, binsum_n, gbase_e, gbase_n);

    // permutation build: deterministic counting-sort partition (0 global atomics,
    // 0 serial prefix loops). tmp arrays alias x1b/xm (dead until pulls).
    unsigned int* tmp_e = (unsigned int*)x1b;
    unsigned int* tmp_n = (unsigned int*)xm;
    bin_coarse<<<NCHUNK, 256, 0, stream>>>(node_idx, edge_idx, gbase_e, gbase_n,
                                           chunkhist_e, chunkhist_n, tmp_e, tmp_n);
    // scatter_fine also builds off[] (per-bucket LDS histogram + scan)
    scatter_fine<<<NBC_E + NBC_N, 256, 0, stream>>>(tmp_e, tmp_n, gbase_e, gbase_n,
                                                    off_e, off_n, perm_e, perm_n);

    // pulls (pair-gather; edge kernel 8 gathers deep)
    pull_edge<<<N_EDGES / 4, 256, 0, stream>>>(x0b, off_e, perm_e, x1, x1b);
    pull_node<<<N_NODES / 4, 256, 0, stream>>>(x0b, x1b, off_n, perm_n, xm);

    // GEMM: out0 = xm @ W^T + b (two blocks per row tile, one per col half)
    const int row_tiles = (N_NODES + 127) / 128;   // 782
    mfma_gemm2<<<row_tiles * 2, 512, 0, stream>>>(xm, Wb, b, out);
}